// Round 1
// baseline (146.471 us; speedup 1.0000x reference)
//
#include <hip/hip_runtime.h>
#include <hip/hip_bf16.h>

// Problem constants
#define N_SRC 100000
#define N_MID 20000
#define N_OUT 5000
#define E_1   20000
#define E_2   20000
#define NCHUNK 33      // 32 W chunks + 1 bias chunk
#define NSPLIT 2       // K-split: chunk ranges {0-17, 17-33}
#define NBLK   313     // ceil(20000/64)

typedef float f32x4 __attribute__((ext_vector_type(4)));
typedef short s16x8 __attribute__((ext_vector_type(8)));   // 8 bf16 = 4 VGPRs

__device__ __forceinline__ void load_lds16(const void* g, void* l) {
    __builtin_amdgcn_global_load_lds(
        (const __attribute__((address_space(1))) unsigned int*)g,
        (__attribute__((address_space(3))) unsigned int*)l, 16, 0, 0);
}

__device__ __forceinline__ s16x8 pack_bf16x8(float4 x, float4 y, float s) {
    union { s16x8 v; __hip_bfloat162 h[4]; } u;
    u.h[0] = __float22bfloat162_rn(make_float2(s * x.x, s * x.y));
    u.h[1] = __float22bfloat162_rn(make_float2(s * x.z, s * x.w));
    u.h[2] = __float22bfloat162_rn(make_float2(s * y.x, s * y.y));
    u.h[3] = __float22bfloat162_rn(make_float2(s * y.z, s * y.w));
    return u.v;
}

__device__ __forceinline__ unsigned short f2bf_rne(float f) {
    unsigned u = __float_as_uint(f);
    return (unsigned short)((u + 0x7FFFu + ((u >> 16) & 1u)) >> 16);
}

__device__ __forceinline__ float4 relu_scale4(float4 v, float s) {
    return make_float4(fmaxf(v.x * s, 0.0f), fmaxf(v.y * s, 0.0f),
                       fmaxf(v.z * s, 0.0f), fmaxf(v.w * s, 0.0f));
}

// Fused setup:
//  (a) prep: fp32 W+bias -> bf16 swizzled [chunk][n][k] layout (both layers)
//  (b) degree count for both layers (atomic; cur1/cur2 pre-zeroed by memset)
//  (c) zero the hsum/outsum accumulators (grid-stride float4 stores)
__global__ void setup_kernel(const float* __restrict__ W1, const float* __restrict__ b1,
                             const float* __restrict__ W2, const float* __restrict__ b2,
                             uint4* __restrict__ Wt1, uint4* __restrict__ Wt2,
                             const int* __restrict__ dst1, const int* __restrict__ dst2,
                             int* __restrict__ cur1, int* __restrict__ cur2,
                             float4* __restrict__ zbase)
{
    int gid = blockIdx.x * 256 + threadIdx.x;

    // ---- (a) weight prep ----
    if (gid < 2 * NCHUNK * 512) {
        int layer = gid / (NCHUNK * 512);
        int r     = gid % (NCHUNK * 512);
        int c  = r / 512;
        int u  = r % 512;
        int k8 = u / 64;
        int n  = u % 64;
        const float* W = layer ? W2 : W1;
        const float* b = layer ? b2 : b1;
        const float* s = (c < 32) ? (W + (size_t)c * 4096) : b;
        union { uint4 v; unsigned short us[8]; } pk;
        #pragma unroll
        for (int j = 0; j < 8; ++j)
            pk.us[j] = f2bf_rne(s[(k8 * 8 + j) * 64 + n]);
        uint4* Wt = layer ? Wt2 : Wt1;
        Wt[(size_t)c * 512 + n * 8 + (k8 ^ (n & 7))] = pk.v;
    }

    // ---- (b) degree counts ----
    if (gid < E_1) {
        atomicAdd(&cur1[dst1[gid]], 1);
    } else if (gid < E_1 + E_2) {
        atomicAdd(&cur2[dst2[gid - E_1]], 1);
    }

    // ---- (c) zero accumulators: (N_MID + N_OUT)*64 floats = 400000 float4 ----
    const int ZN4 = (N_MID + N_OUT) * 16;
    for (int i = gid; i < ZN4; i += gridDim.x * 256)
        zbase[i] = make_float4(0.0f, 0.0f, 0.0f, 0.0f);
}

// Fused NNConv message GEMM (MFMA) with direct atomic scatter-add into dst rows.
// acc[e][o] = sum_{c in split} ef[e,c] * (hs[e,:] @ Wc)   (c==32: bias, ef=1)
// NORM: input h is an unnormalized sum; apply relu(h * 1/deg) at load (layer 2).
template<int NORM>
__global__ __launch_bounds__(256) void nnconv_mfma(
    const float* __restrict__ h,      // [n_rows, 64] fp32
    const float* __restrict__ efeat,  // [E, 32] fp32
    const uint4* __restrict__ Wt,     // [33][512] swizzled bf16 units
    const int*  __restrict__ src,
    const int*  __restrict__ dstv,
    const int*  __restrict__ degs,    // degree of input rows (NORM only)
    int E,
    float* __restrict__ outacc)       // [n_dst, 64] fp32, atomically accumulated
{
    __shared__ float efs[64][17];         // [edge][c - c_lo], split range <= 17 chunks
    __shared__ uint4 wbuf[2][512];        // double-buffered W chunk (8 KB each)

    const int t  = threadIdx.x;
    const int w  = t >> 6;                // wave 0..3
    const int l  = t & 63;
    const int m15 = l & 15;               // MFMA row (A) / col (B,C)
    const int q   = l >> 4;               // quad 0..3
    const int ebase = blockIdx.x * 64;
    const int split = blockIdx.y;
    const int c_lo = split ? 17 : 0;
    const int c_hi = split ? 33 : 17;
    const int nc   = c_hi - c_lo;         // 17 or 16

    // ---- stage this split's edge-feature columns (bias col -> 1.0) ----
    for (int idx = t; idx < 64 * nc; idx += 256) {
        int e = idx / nc, j = idx - e * nc;
        int eg = ebase + e, f = c_lo + j;
        float v = 0.0f;
        if (eg < E) v = (f < 32) ? efeat[eg * 32 + f] : 1.0f;
        efs[e][j] = v;
    }

    // ---- issue first W chunk into wbuf[0] ----
    {
        const uint4* g = Wt + (size_t)c_lo * 512;
        load_lds16(g + t,       &wbuf[0][t]);
        load_lds16(g + 256 + t, &wbuf[0][256 + t]);
    }

    // ---- preload dst rows for this wave's 16 edges (overlaps staging) ----
    int dv[4];
    #pragma unroll
    for (int r = 0; r < 4; ++r) {
        int e = ebase + w * 16 + q * 4 + r;
        dv[r] = (e < E) ? dstv[e] : 0;     // padded edges accumulate 0.0 into row 0
    }

    // ---- A-frag fp32 preload (gather, once per block) ----
    const int e_a = ebase + w * 16 + m15;
    const int row = (e_a < E) ? src[e_a] : 0;
    const float* hp = h + (size_t)row * 64 + q * 8;
    float4 ha0 = *(const float4*)(hp);
    float4 ha1 = *(const float4*)(hp + 4);
    float4 hb0 = *(const float4*)(hp + 32);
    float4 hb1 = *(const float4*)(hp + 36);
    if (NORM) {
        const float rd = 1.0f / fmaxf((float)degs[row], 1.0f);
        ha0 = relu_scale4(ha0, rd);
        ha1 = relu_scale4(ha1, rd);
        hb0 = relu_scale4(hb0, rd);
        hb1 = relu_scale4(hb1, rd);
    }

    f32x4 acc[4] = {};
    const int nx = m15 & 7;

    int cur = 0;
    for (int c = c_lo; c < c_hi; ++c) {
        __syncthreads();                          // wbuf[cur] resident
        if (c + 1 < c_hi) {
            const uint4* g = Wt + (size_t)(c + 1) * 512;
            load_lds16(g + t,       &wbuf[cur ^ 1][t]);
            load_lds16(g + 256 + t, &wbuf[cur ^ 1][256 + t]);
        }
        const float ef = efs[w * 16 + m15][c - c_lo];
        const s16x8 a0 = pack_bf16x8(ha0, ha1, ef);   // k 0..31
        const s16x8 a1 = pack_bf16x8(hb0, hb1, ef);   // k 32..63
        const uint4* wb = wbuf[cur];
        #pragma unroll
        for (int c16 = 0; c16 < 4; ++c16) {
            const int n = c16 * 16 + m15;
            const s16x8 b0 = *(const s16x8*)&wb[n * 8 + ((q)     ^ nx)];
            const s16x8 b1 = *(const s16x8*)&wb[n * 8 + ((4 + q) ^ nx)];
            acc[c16] = __builtin_amdgcn_mfma_f32_16x16x32_bf16(a0, b0, acc[c16], 0, 0, 0);
            acc[c16] = __builtin_amdgcn_mfma_f32_16x16x32_bf16(a1, b1, acc[c16], 0, 0, 0);
        }
        cur ^= 1;
    }

    // ---- epilogue: direct scatter-add. lane holds D[m=q*4+r][n=c16*16+m15] ----
    #pragma unroll
    for (int r = 0; r < 4; ++r) {
        float* rp = outacc + (size_t)dv[r] * 64 + m15;
        #pragma unroll
        for (int c16 = 0; c16 < 4; ++c16)
            unsafeAtomicAdd(rp + c16 * 16, acc[c16][r]);
    }
}

// out[d, o] = outsum[d, o] / max(deg[d], 1)    (no relu on final layer)
__global__ void finalize_kernel(const float4* __restrict__ outsum,
                                const int* __restrict__ cur,
                                float4* __restrict__ outp)
{
    int i = blockIdx.x * 256 + threadIdx.x;      // one float4 each; 5000*16 total
    if (i >= N_OUT * 16) return;
    int d = i >> 4;
    float rd = 1.0f / fmaxf((float)cur[d], 1.0f);
    float4 v = outsum[i];
    v.x *= rd; v.y *= rd; v.z *= rd; v.w *= rd;
    outp[i] = v;
}

extern "C" void kernel_launch(void* const* d_in, const int* in_sizes, int n_in,
                              void* d_out, int out_size, void* d_ws, size_t ws_size,
                              hipStream_t stream)
{
    const float* in_feat = (const float*)d_in[0];
    const float* ef1     = (const float*)d_in[1];
    const float* ef2     = (const float*)d_in[2];
    const float* W1      = (const float*)d_in[3];
    const float* b1      = (const float*)d_in[4];
    const float* W2      = (const float*)d_in[5];
    const float* b2      = (const float*)d_in[6];
    const int*   src1    = (const int*)d_in[7];
    const int*   dst1    = (const int*)d_in[8];
    const int*   src2    = (const int*)d_in[9];
    const int*   dst2    = (const int*)d_in[10];

    // Workspace layout (Wt first for 16B alignment)
    uint4* Wt1    = (uint4*)d_ws;                        // [33*512]
    uint4* Wt2    = Wt1 + (size_t)NCHUNK * 512;          // [33*512]
    float* hsum   = (float*)(Wt2 + (size_t)NCHUNK * 512);// [20000*64] atomic accum
    float* outsum = hsum + (size_t)N_MID * 64;           // [5000*64]  atomic accum
    int*   cur1   = (int*)(outsum + (size_t)N_OUT * 64); // [20000] degrees
    int*   cur2   = cur1 + N_MID;                        // [5000]  degrees
    float* out    = (float*)d_out;                       // [5000*64]

    // only the degree counters need memset; accumulators zeroed inside setup
    hipMemsetAsync(cur1, 0, (size_t)(N_MID + N_OUT) * sizeof(int), stream);

    setup_kernel<<<1024, 256, 0, stream>>>(W1, b1, W2, b2, Wt1, Wt2,
                                           dst1, dst2, cur1, cur2, (float4*)hsum);

    dim3 grid(NBLK, NSPLIT);
    nnconv_mfma<0><<<grid, 256, 0, stream>>>(in_feat, ef1, Wt1, src1, dst1,
                                             nullptr, E_1, hsum);
    nnconv_mfma<1><<<grid, 256, 0, stream>>>(hsum, ef2, Wt2, src2, dst2,
                                             cur1, E_2, outsum);
    finalize_kernel<<<(N_OUT * 16 + 255) / 256, 256, 0, stream>>>(
        (const float4*)outsum, cur2, (float4*)out);
}